// Round 11
// baseline (257.335 us; speedup 1.0000x reference)
//
#include <hip/hip_runtime.h>

typedef short short8 __attribute__((ext_vector_type(8)));
typedef float f32x4 __attribute__((ext_vector_type(4)));
typedef unsigned u32x4 __attribute__((ext_vector_type(4)));

// ---------------- bf16 helpers ----------------

__device__ inline unsigned short f2bf(float f) {
    union { float f; unsigned u; } v; v.f = f;
    unsigned r = v.u + 0x7fffu + ((v.u >> 16) & 1u);
    return (unsigned short)(r >> 16);
}
__device__ inline unsigned pack2(float a, float b) {
    return (unsigned)f2bf(a) | ((unsigned)f2bf(b) << 16);
}
__device__ inline float bflo(unsigned u) { union { unsigned q; float f; } c; c.q = u << 16; return c.f; }
__device__ inline float bfhi(unsigned u) { union { unsigned q; float f; } c; c.q = u & 0xffff0000u; return c.f; }

#define ACC8(vv)                                     \
    acc[0] += bflo(vv.x); acc[1] += bfhi(vv.x);      \
    acc[2] += bflo(vv.y); acc[3] += bfhi(vv.y);      \
    acc[4] += bflo(vv.z); acc[5] += bfhi(vv.z);      \
    acc[6] += bflo(vv.w); acc[7] += bfhi(vv.w);

// ---------------- CSR build: direct-scatter bucket sort (R9, unchanged) ----------------

#define EPB 2048
#define NE 8
#define BSH 9
#define MAXBKT 128
#define DCAP 10240
#define BCAP 16384

__global__ __launch_bounds__(256) void megaA(
    const int* __restrict__ src, const int* __restrict__ dst,
    int* __restrict__ cursor, unsigned* __restrict__ pairs,
    int e, int nbkt, int nblk,
    const float4* __restrict__ feat, uint4* __restrict__ featb, int cvtb, int n16, int np,
    const float* __restrict__ W1, const float* __restrict__ Wh, const float* __restrict__ Wo,
    unsigned short* __restrict__ W1t, unsigned short* __restrict__ Wht,
    unsigned short* __restrict__ Wot) {
    __shared__ int hist[MAXBKT], loff[MAXBKT], cur[MAXBKT], gb[MAXBKT];
    __shared__ int sc[256];
    __shared__ unsigned sorted[EPB];
    int t = threadIdx.x, blk = blockIdx.x;
    if (blk < nblk) {
        for (int b = t; b < nbkt; b += 256) hist[b] = 0;
        __syncthreads();
        int base = blk * EPB;
        int cnt = min(EPB, e - base);
        unsigned packed[NE];
        int bb[NE];
#pragma unroll
        for (int j = 0; j < NE; j++) {
            int idx = base + t + 256 * j;
            bb[j] = -1;
            if (idx < e) {
                unsigned s0 = (unsigned)src[idx], d = (unsigned)dst[idx];
                int b = (int)(d >> BSH);
                bb[j] = b;
                packed[j] = s0 | ((d & ((1u << BSH) - 1)) << 16) | ((unsigned)b << 25);
                atomicAdd(&hist[b], 1);
            }
        }
        __syncthreads();
        int v = (t < nbkt) ? hist[t] : 0;
        sc[t] = v;
        __syncthreads();
        for (int off = 1; off < 256; off <<= 1) {
            int u = (t >= off) ? sc[t - off] : 0;
            __syncthreads();
            sc[t] += u;
            __syncthreads();
        }
        if (t < nbkt) {
            int ex = sc[t] - v;
            loff[t] = ex;
            cur[t] = ex;
            gb[t] = t * BCAP + (v ? atomicAdd(&cursor[t], v) : atomicAdd(&cursor[t], 0));
        }
        __syncthreads();
#pragma unroll
        for (int j = 0; j < NE; j++) {
            if (bb[j] >= 0) {
                int r = atomicAdd(&cur[bb[j]], 1);  // LDS only
                sorted[r] = packed[j];
            }
        }
        __syncthreads();
        for (int i = t; i < cnt; i += 256) {
            unsigned w = sorted[i];
            int b = (int)(w >> 25);
            pairs[gb[b] + (i - loff[b])] = w;
        }
    } else if (blk < nblk + cvtb) {
        int i = (blk - nblk) * 256 + t;
        if (i < n16) {  // plane-split bf16 conversion: plane q holds chunks [4q,4q+4)
            int node = i >> 4, chunk = i & 15;
            int q = chunk >> 2, c4 = chunk & 3;
            float4 a = feat[2 * i], b = feat[2 * i + 1];
            uint4 pk = make_uint4(pack2(a.x, a.y), pack2(a.z, a.w),
                                  pack2(b.x, b.y), pack2(b.z, b.w));
            featb[(size_t)q * (np * 4) + (size_t)node * 4 + c4] = pk;
        }
    } else {
        int i = (blk - nblk - cvtb) * 256 + t;
        if (i < 16384) {
            int k = i >> 7, nn = i & 127;
            W1t[nn * 128 + k] = f2bf(W1[i]);
        } else if (i < 32768) {
            int j = i - 16384, k = j >> 7, nn = j & 127;
            Wht[nn * 128 + k] = f2bf(Wh[j]);
        } else if (i < 40960) {
            int j = i - 32768, k = j >> 6, nn = j & 63;
            Wot[nn * 128 + k] = f2bf(Wo[j]);
        }
    }
}

__global__ __launch_bounds__(512) void buildD(const unsigned* __restrict__ pairs,
                                              const int* __restrict__ cursor,
                                              int* __restrict__ row_ptr, int* __restrict__ row_end,
                                              unsigned short* __restrict__ csr, int n) {
    __shared__ int hist[512], off[512];
    __shared__ unsigned short lcsr[DCAP];
    int t = threadIdx.x, b = blockIdx.x;
    int cnt = cursor[b], base = b * BCAP;
    hist[t] = 0;
    __syncthreads();
    for (int i = t; i < cnt; i += 512)
        atomicAdd(&hist[(pairs[base + i] >> 16) & 511], 1);
    __syncthreads();
    int v = hist[t];
    off[t] = v;
    __syncthreads();
    for (int o = 1; o < 512; o <<= 1) {
        int u = (t >= o) ? off[t - o] : 0;
        __syncthreads();
        off[t] += u;
        __syncthreads();
    }
    int excl = off[t] - v;
    int node = (b << BSH) + t;
    if (node < n) {
        row_ptr[node] = base + excl;
        row_end[node] = base + off[t];
    }
    __syncthreads();
    hist[t] = excl;
    __syncthreads();
    for (int i = t; i < cnt; i += 512) {
        unsigned w = pairs[base + i];
        int r = atomicAdd(&hist[(w >> 16) & 511], 1);  // LDS only
        if (r < DCAP) lcsr[r] = (unsigned short)(w & 0xFFFFu);
    }
    __syncthreads();
    int lim = min(cnt, DCAP);
    for (int i = t; i < lim; i += 512) csr[base + i] = lcsr[i];
}

// ---------------- Plane-split aggregation ----------------
// x is NSPLIT planes of np*4 uint4 (each plane = 64B/row slice). q = blockIdx % NSPLIT:
// round-robin block->XCD dispatch pins one 3.2MB plane per XCD L2.
// Wave: 4 node-groups (divergent, R6-style MLP) x [4 chunk-lanes x 4 edge-slots].
// Per load-inst: 16 rows in flight; 4-deep unroll -> 64 rows/wave outstanding.

#define ECAP 1024

template <int NSPLIT, bool OUTF32>
__global__ __launch_bounds__(256) void agg_plane(
    const uint4* __restrict__ x, void* __restrict__ outp,
    const int* __restrict__ row_ptr, const int* __restrict__ row_end,
    const unsigned short* __restrict__ csr, int n, int np) {
    __shared__ unsigned short eidx[ECAP];
    int q = (int)(blockIdx.x % NSPLIT);
    int nb = (int)(blockIdx.x / NSPLIT);
    int t = threadIdx.x;
    int r0 = nb * 16;
    int wid = t >> 6, lane = t & 63;
    int group = lane >> 4;         // node-group within wave
    int chunk4 = lane & 3;         // uint4 within this plane's 64B slice
    int eslot = (lane >> 2) & 3;   // edge slot
    int nl = wid * 4 + group;
    int node = r0 + nl;

    int E0 = row_ptr[min(r0, n - 1)];
    int E1 = row_end[min(r0 + 15, n - 1)];
    int ecnt = min(E1 - E0, ECAP);
    bool staged = (E1 - E0) <= ECAP;
    for (int i = t; i < ecnt; i += 256)
        eidx[i] = __builtin_nontemporal_load(&csr[E0 + i]);
    __syncthreads();

    const uint4* xq = x + (size_t)q * np * 4;
    float acc[8] = {0.f, 0.f, 0.f, 0.f, 0.f, 0.f, 0.f, 0.f};
    if (node < n) {
        if (eslot == 0) {
            uint4 s0 = xq[(size_t)node * 4 + chunk4];
            ACC8(s0)
        }
        int beg = row_ptr[node], end = row_end[node];
        if (staged) {
            beg -= E0; end -= E0;
            int k = beg + eslot;
            for (; k + 12 < end; k += 16) {
                int i0 = eidx[k], i1 = eidx[k + 4], i2 = eidx[k + 8], i3 = eidx[k + 12];
                uint4 v0 = xq[(size_t)i0 * 4 + chunk4];
                uint4 v1 = xq[(size_t)i1 * 4 + chunk4];
                uint4 v2 = xq[(size_t)i2 * 4 + chunk4];
                uint4 v3 = xq[(size_t)i3 * 4 + chunk4];
                ACC8(v0) ACC8(v1) ACC8(v2) ACC8(v3)
            }
            for (; k < end; k += 4) {
                uint4 v = xq[(size_t)eidx[k] * 4 + chunk4];
                ACC8(v)
            }
        } else {
            int k = beg + eslot;
            for (; k + 12 < end; k += 16) {
                int i0 = csr[k], i1 = csr[k + 4], i2 = csr[k + 8], i3 = csr[k + 12];
                uint4 v0 = xq[(size_t)i0 * 4 + chunk4];
                uint4 v1 = xq[(size_t)i1 * 4 + chunk4];
                uint4 v2 = xq[(size_t)i2 * 4 + chunk4];
                uint4 v3 = xq[(size_t)i3 * 4 + chunk4];
                ACC8(v0) ACC8(v1) ACC8(v2) ACC8(v3)
            }
            for (; k < end; k += 4) {
                uint4 v = xq[(size_t)csr[k] * 4 + chunk4];
                ACC8(v)
            }
        }
    }
    // fold the 4 edge-slots (lane bits 2,3)
#pragma unroll
    for (int j = 0; j < 8; j++) {
        acc[j] += __shfl_xor(acc[j], 4, 64);
        acc[j] += __shfl_xor(acc[j], 8, 64);
    }
    if (node < n && eslot == 0) {
        if (OUTF32) {
            // layer-3 (NSPLIT=2): row-major fp32 z, half q at 128B offset
            f32x4* o = (f32x4*)((float*)outp + (size_t)node * 64 + (q * 4 + chunk4) * 8);
            f32x4 o0 = {acc[0], acc[1], acc[2], acc[3]};
            f32x4 o1 = {acc[4], acc[5], acc[6], acc[7]};
            __builtin_nontemporal_store(o0, o);
            __builtin_nontemporal_store(o1, o + 1);
        } else {
            u32x4 pk = {pack2(acc[0], acc[1]), pack2(acc[2], acc[3]),
                        pack2(acc[4], acc[5]), pack2(acc[6], acc[7])};
            __builtin_nontemporal_store(
                pk, (u32x4*)outp + (size_t)q * np * 4 + (size_t)node * 4 + chunk4);
        }
    }
}

// ---------------- GEMM via MFMA bf16, plane-split A; SECOND chains y = relu(h)@Wo ----------------

template <int OUT, bool SECOND>
__global__ __launch_bounds__(256) void gemm_mfma(
    const short8* __restrict__ A,   // 4 planes of np*4 short8
    const short8* __restrict__ Bt,
    const float* __restrict__ bias, unsigned short* __restrict__ outp,
    const short8* __restrict__ Bt2, unsigned short* __restrict__ out_y,
    int n, int np) {
    constexpr int NT = OUT / 16;
    __shared__ unsigned short Hs[SECOND ? 4 : 1][16][136];
    int t = threadIdx.x;
    int wid = t >> 6, lane = t & 63, lm = lane & 15, lq = lane >> 4;
    int r0 = blockIdx.x * 64 + wid * 16;
    int arow = min(r0 + lm, n - 1);
    short8 a[4];
#pragma unroll
    for (int kc = 0; kc < 4; kc++)
        a[kc] = A[((size_t)kc * np + arow) * 4 + lq];

    f32x4 acc[NT];
#pragma unroll
    for (int nt = 0; nt < NT; nt++) acc[nt] = (f32x4){0.f, 0.f, 0.f, 0.f};
#pragma unroll
    for (int nt = 0; nt < NT; nt++) {
        const short8* Br = Bt + (size_t)(nt * 16 + lm) * 16;
#pragma unroll
        for (int kc = 0; kc < 4; kc++)
            acc[nt] = __builtin_amdgcn_mfma_f32_16x16x32_bf16(a[kc], Br[kc * 4 + lq], acc[nt], 0, 0, 0);
    }

#pragma unroll
    for (int nt = 0; nt < NT; nt++) {
        int col = nt * 16 + lm;
        float bv = bias[col];
#pragma unroll
        for (int i = 0; i < 4; i++) {
            int row = r0 + lq * 4 + i;
            float v = fmaxf(acc[nt][i] + bv, 0.f);
            if (SECOND) {
                Hs[wid][lq * 4 + i][col] = f2bf(v);
            } else if (row < n) {
                // plane-split write: plane col>>5, 32 cols per plane
                outp[((size_t)(col >> 5) * np + row) * 32 + (col & 31)] = f2bf(v);
            }
        }
    }

    if (SECOND) {
        short8 a2[4];
#pragma unroll
        for (int kc = 0; kc < 4; kc++)
            a2[kc] = *(const short8*)&Hs[wid][lm][kc * 32 + lq * 8];
        f32x4 yacc[4];
#pragma unroll
        for (int ct = 0; ct < 4; ct++) yacc[ct] = (f32x4){0.f, 0.f, 0.f, 0.f};
#pragma unroll
        for (int ct = 0; ct < 4; ct++) {
            const short8* Br2 = Bt2 + (size_t)(ct * 16 + lm) * 16;
#pragma unroll
            for (int kc = 0; kc < 4; kc++)
                yacc[ct] = __builtin_amdgcn_mfma_f32_16x16x32_bf16(a2[kc], Br2[kc * 4 + lq], yacc[ct], 0, 0, 0);
        }
#pragma unroll
        for (int ct = 0; ct < 4; ct++) {
            int col = ct * 16 + lm;
#pragma unroll
            for (int i = 0; i < 4; i++) {
                int row = r0 + lq * 4 + i;
                if (row < n)
                    out_y[((size_t)(col >> 5) * np + row) * 32 + (col & 31)] = f2bf(yacc[ct][i]);
            }
        }
    }
}

// ---------------- log_softmax over 64 cols (+bo) ----------------

__global__ __launch_bounds__(256) void lsm_kernel(const float4* __restrict__ z,
                                                  const float* __restrict__ bo,
                                                  float* __restrict__ out, int n) {
    int t = threadIdx.x;
    int node = blockIdx.x * 32 + (t >> 3), lane = t & 7;
    if (node >= n) return;
    float4 v0 = z[(size_t)node * 16 + lane * 2];
    float4 v1 = z[(size_t)node * 16 + lane * 2 + 1];
    const float4* bo4 = (const float4*)bo;
    float4 bA = bo4[lane * 2], bB = bo4[lane * 2 + 1];
    float acc[8] = { v0.x + bA.x, v0.y + bA.y, v0.z + bA.z, v0.w + bA.w,
                     v1.x + bB.x, v1.y + bB.y, v1.z + bB.z, v1.w + bB.w };
    float m = acc[0];
#pragma unroll
    for (int j = 1; j < 8; j++) m = fmaxf(m, acc[j]);
#pragma unroll
    for (int off = 1; off < 8; off <<= 1) m = fmaxf(m, __shfl_xor(m, off, 64));
    float s = 0.f;
#pragma unroll
    for (int j = 0; j < 8; j++) s += __expf(acc[j] - m);
#pragma unroll
    for (int off = 1; off < 8; off <<= 1) s += __shfl_xor(s, off, 64);
    float ls = m + __logf(s);
    float4* op = (float4*)(out + (size_t)node * 64 + lane * 8);
    op[0] = make_float4(acc[0] - ls, acc[1] - ls, acc[2] - ls, acc[3] - ls);
    op[1] = make_float4(acc[4] - ls, acc[5] - ls, acc[6] - ls, acc[7] - ls);
}

// ---------------- launch ----------------

extern "C" void kernel_launch(void* const* d_in, const int* in_sizes, int n_in,
                              void* d_out, int out_size, void* d_ws, size_t ws_size,
                              hipStream_t stream) {
    const float* feature = (const float*)d_in[0];
    const int*   edges   = (const int*)d_in[1];
    const float* W1 = (const float*)d_in[2];
    const float* b1 = (const float*)d_in[3];
    const float* Wh = (const float*)d_in[4];
    const float* bh = (const float*)d_in[5];
    const float* Wo = (const float*)d_in[6];
    const float* bo = (const float*)d_in[7];

    int n = in_sizes[0] / 128;  // 50000 (< 65536 for 16-bit src packing)
    int e = in_sizes[1] / 2;    // 800000
    const int* src = edges;
    const int* dst = edges + e;
    int np = n;

    int nbkt = (n + 511) >> BSH;       // 98
    int nblk = (e + EPB - 1) / EPB;    // 391
    int n16 = n * 16;
    int cvtb = (n16 + 255) / 256;

    char* ws = (char*)d_ws;
    auto take = [&](size_t bytes) {
        char* p = ws;
        ws += (bytes + 255) & ~(size_t)255;
        return p;
    };
    int* cursor  = (int*)take((size_t)nbkt * 4);
    int* row_ptr = (int*)take((size_t)n * 4);
    int* row_end = (int*)take((size_t)n * 4);
    unsigned* pairs = (unsigned*)take((size_t)nbkt * BCAP * 4);
    unsigned short* csr = (unsigned short*)take((size_t)nbkt * BCAP * 2);
    unsigned short* featb = (unsigned short*)take((size_t)n * 128 * 2);
    unsigned short* aggb  = (unsigned short*)take((size_t)n * 128 * 2);
    unsigned short* hb    = (unsigned short*)take((size_t)n * 128 * 2);
    unsigned short* yb    = (unsigned short*)take((size_t)n * 64 * 2);
    float*          zf    = (float*)take((size_t)n * 64 * 4);
    unsigned short* W1t = (unsigned short*)take(128 * 128 * 2);
    unsigned short* Wht = (unsigned short*)take(128 * 128 * 2);
    unsigned short* Wot = (unsigned short*)take(64 * 128 * 2);

    hipMemsetAsync(cursor, 0, (size_t)nbkt * 4, stream);
    megaA<<<nblk + cvtb + 160, 256, 0, stream>>>(
        src, dst, cursor, pairs, e, nbkt, nblk,
        (const float4*)feature, (uint4*)featb, cvtb, n16, np,
        W1, Wh, Wo, W1t, Wht, Wot);
    buildD<<<nbkt, 512, 0, stream>>>(pairs, cursor, row_ptr, row_end, csr, n);

    int fblocks = (n + 15) / 16;  // 3125

    // Layer 1: a1 = x + agg(x) (plane-split); h1 = relu(a1@W1+b1) (plane-split)
    agg_plane<4, false><<<fblocks * 4, 256, 0, stream>>>(
        (const uint4*)featb, aggb, row_ptr, row_end, csr, n, np);
    gemm_mfma<128, false><<<(n + 63) / 64, 256, 0, stream>>>(
        (const short8*)aggb, (const short8*)W1t, b1, hb, nullptr, nullptr, n, np);

    // Layer 2: a2 = h1 + agg(h1); h2 = relu(a2@Wh+bh); y = h2@Wo (chained, halves)
    agg_plane<4, false><<<fblocks * 4, 256, 0, stream>>>(
        (const uint4*)hb, aggb, row_ptr, row_end, csr, n, np);
    gemm_mfma<128, true><<<(n + 63) / 64, 256, 0, stream>>>(
        (const short8*)aggb, (const short8*)Wht, bh, nullptr, (const short8*)Wot, yb, n, np);

    // Layer 3: z = y + agg(y) (halves -> row-major fp32); out = log_softmax(z+bo)
    agg_plane<2, true><<<fblocks * 2, 256, 0, stream>>>(
        (const uint4*)yb, zf, row_ptr, row_end, csr, n, np);
    lsm_kernel<<<(n + 31) / 32, 256, 0, stream>>>(
        (const float4*)zf, bo, (float*)d_out, n);
}